// Round 1
// 301.240 us; speedup vs baseline: 1.1588x; 1.1588x over previous
//
#include <hip/hip_runtime.h>

// ---------------------------------------------------------------------------
// B=8, S=4096 (rows=32768), D=1024, DS=64
// segments: qk 512 (tiles 0-31) | v 256 (32-47) | rel 128 (48-55) | val 64 (56-59)
// R4: fuse proj+agg into k_main. x staged via global_load_lds (3-buf, counted
// vmcnt, raw barriers), XOR-swizzled LDS (pre-swizzled global src), cvt_pk
// bf16 split, register prefetch of both B operands. h exchanged via LDS.
// ---------------------------------------------------------------------------

typedef short short8 __attribute__((ext_vector_type(8)));   // 8 bf16 = 4 VGPR
typedef float f32x4 __attribute__((ext_vector_type(4)));
typedef unsigned int uint4v __attribute__((ext_vector_type(4)));

__device__ __forceinline__ unsigned short f32_to_bf16(float f) {
  unsigned u = __float_as_uint(f);
  u += 0x7FFF + ((u >> 16) & 1);  // RNE
  return (unsigned short)(u >> 16);
}
__device__ __forceinline__ float bf16_to_f32(unsigned short h) {
  return __uint_as_float(((unsigned)h) << 16);
}

// packed f32->bf16 RNE, 2 at a time (hw instruction; low half = first operand)
__device__ __forceinline__ unsigned cvt_pk_bf16(float a, float b) {
  unsigned r;
  asm("v_cvt_pk_bf16_f32 %0, %1, %2" : "=v"(r) : "v"(a), "v"(b));
  return r;
}

// split 8 f32 -> hi/lo bf16 frags (hi = RNE(v), lo = RNE(v - hi))
__device__ __forceinline__ void split8v(const f32x4& v0, const f32x4& v1,
                                        short8& hi, short8& lo) {
  unsigned hp[4], lp[4];
#pragma unroll
  for (int j = 0; j < 4; ++j) {
    float a = (j < 2) ? v0[2 * j] : v1[2 * j - 4];
    float b = (j < 2) ? v0[2 * j + 1] : v1[2 * j - 3];
    unsigned p = cvt_pk_bf16(a, b);
    float ra = a - __uint_as_float(p << 16);
    float rb = b - __uint_as_float(p & 0xFFFF0000u);
    hp[j] = p;
    lp[j] = cvt_pk_bf16(ra, rb);
  }
  hi = __builtin_bit_cast(short8, (uint4v){hp[0], hp[1], hp[2], hp[3]});
  lo = __builtin_bit_cast(short8, (uint4v){lp[0], lp[1], lp[2], lp[3]});
}

#define MFMA(a, b, c) __builtin_amdgcn_mfma_f32_16x16x32_bf16(a, b, c, 0, 0, 0)

typedef const __attribute__((address_space(1))) unsigned int guint;
typedef __attribute__((address_space(3))) unsigned int luint;
// async global->LDS, 16 B per lane; LDS dest = wave-uniform base + lane*16
__device__ __forceinline__ void stage16(const float* g, float* l) {
  __builtin_amdgcn_global_load_lds((guint*)g, (luint*)l, 16, 0, 0);
}
__device__ __forceinline__ void bar() {
  asm volatile("" ::: "memory");
  __builtin_amdgcn_s_barrier();
  asm volatile("" ::: "memory");
}

// ---- k_prep: zero wg; split proj_w -> whi/wlo; normalize+split emb -> ehi/elo ----
__global__ __launch_bounds__(256) void k_prep(const float* __restrict__ pw,
                                              const float* __restrict__ emb,
                                              unsigned short* __restrict__ whi,
                                              unsigned short* __restrict__ wlo,
                                              unsigned short* __restrict__ ehi,
                                              unsigned short* __restrict__ elo,
                                              float* __restrict__ wg) {
  int tid = blockIdx.x * 256 + threadIdx.x;
  if (tid < 7680) wg[tid] = 0.f;
  for (int i = tid; i < 65536; i += gridDim.x * 256) {
    float v = pw[i];
    unsigned short h = f32_to_bf16(v);
    whi[i] = h;
    wlo[i] = f32_to_bf16(v - bf16_to_f32(h));
  }
  int wid = tid >> 6, lane = tid & 63;
  int nw = gridDim.x * 4;
  for (int n = wid; n < 960; n += nw) {
    float v = emb[n * 64 + lane];
    float s = v * v;
#pragma unroll
    for (int off = 1; off < 64; off <<= 1) s += __shfl_xor(s, off);
    float vn = v / sqrtf(s);
    unsigned short h = f32_to_bf16(vn);
    ehi[n * 64 + lane] = h;
    elo[n * 64 + lane] = f32_to_bf16(vn - bf16_to_f32(h));
  }
}

// ---- k_main: fused proj (x@W^T+b) + agg (softmax-weighted emb logits) ----
// grid 1024 x 256thr; block = 32 rows; wave w owns proj N-tile nt=w.
// Proj: x staged to LDS via global_load_lds, 3 buffers, depth-2 prefetch,
// counted vmcnt + raw barriers. LDS is XOR-swizzled (pre-swizzled global src)
// so ds_read_b128 A-frags are conflict-free. h (hi/lo bf16) exchanged through
// LDS into agg A-frags that persist in VGPRs for both agg passes.
__global__ __launch_bounds__(256, 4) void k_main(
    const float* __restrict__ x, const unsigned short* __restrict__ whi,
    const unsigned short* __restrict__ wlo, const float* __restrict__ pb,
    const unsigned short* __restrict__ ehi, const unsigned short* __restrict__ elo,
    const float* __restrict__ imp, float* __restrict__ wg) {
  __shared__ __align__(16) float xt[3][32][32];           // 12 KiB staging
  __shared__ __align__(16) unsigned short hxh[32][64];    // 4 KiB h hi
  __shared__ __align__(16) unsigned short hxl[32][64];    // 4 KiB h lo
  __shared__ float zpart[4][32][4];
  __shared__ float coefL[32][4];

  const int tid = threadIdx.x, w = tid >> 6, lane = tid & 63;
  const int q = lane >> 4, c = lane & 15;
  const int row0 = blockIdx.x * 32;
  const int nt0 = w;

  // staging: thread t fills LDS bytes [t*16,t*16+16) = row t>>3, phys slot t&7.
  // desired layout: phys_colbyte = logical_colbyte ^ ((row&7)<<4)  -> source
  // col is pre-swizzled so LDS dest stays linear (global_load_lds requirement).
  const int srow = tid >> 3;
  const int scol = ((tid & 7) ^ (srow & 7)) * 4;
  const float* sbase = x + (size_t)(row0 + srow) * 1024 + scol;
  auto STAGEX = [&](int slot, int ks) {
    stage16(sbase + ks * 32, &xt[slot][0][0] + (w << 8));  // wave base: w*1KiB
  };

  // proj B (W^T) fragment pointers, register-prefetched 1 kstep ahead
  const unsigned short* bwh = whi + (size_t)(nt0 * 16 + c) * 1024 + q * 8;
  const unsigned short* bwl = wlo + (size_t)(nt0 * 16 + c) * 1024 + q * 8;

  f32x4 acc0 = {0.f, 0.f, 0.f, 0.f}, acc1 = {0.f, 0.f, 0.f, 0.f};

  // swizzled read offsets (hoisted; per-thread constant)
  const unsigned sw = (unsigned)((c & 7) << 4);
  const unsigned off1 = ((unsigned)(q * 32)) ^ sw;
  const unsigned off2 = ((unsigned)(q * 32 + 16)) ^ sw;
  const char* xby = (const char*)&xt[0][0][0] + (size_t)c * 128;

  auto projstep = [&](int slot, short8 B_hi, short8 B_lo) {
    const char* bp = xby + slot * 4096;
    f32x4 a0 = *(const f32x4*)(bp + off1);          // rows c      (mt=0)
    f32x4 a1 = *(const f32x4*)(bp + off2);
    f32x4 a2 = *(const f32x4*)(bp + 2048 + off1);   // rows 16+c   (mt=1)
    f32x4 a3 = *(const f32x4*)(bp + 2048 + off2);
    short8 ah, al;
    split8v(a0, a1, ah, al);
    acc0 = MFMA(ah, B_hi, acc0);
    acc0 = MFMA(ah, B_lo, acc0);
    acc0 = MFMA(al, B_hi, acc0);
    split8v(a2, a3, ah, al);
    acc1 = MFMA(ah, B_hi, acc1);
    acc1 = MFMA(ah, B_lo, acc1);
    acc1 = MFMA(al, B_hi, acc1);
  };

  // ---------------- proj K-loop: 32 ksteps, 3-buffer pipeline ----------------
  STAGEX(0, 0);
  STAGEX(1, 1);
  short8 bh = *(const short8*)bwh;
  short8 bl = *(const short8*)bwl;
  short8 bh_n, bl_n;
  int slot = 0;
  for (int ks = 0; ks < 30; ++ks) {
    int wslot = slot + 2; if (wslot >= 3) wslot -= 3;
    STAGEX(wslot, ks + 2);
    bh_n = *(const short8*)(bwh + (ks + 1) * 32);
    bl_n = *(const short8*)(bwl + (ks + 1) * 32);
    // outstanding newer than STAGE(ks): STAGE(ks+1), B(ks)x2, STAGE(ks+2), B(ks+1)x2 = 6
    asm volatile("s_waitcnt vmcnt(6)" ::: "memory");
    bar();
    projstep(slot, bh, bl);
    bar();
    bh = bh_n; bl = bl_n;
    ++slot; if (slot == 3) slot = 0;
  }
  // ks = 30: no STAGE(32); newer than STAGE(30): STAGE(31), B(30)x2, B(31)x2 = 5
  bh_n = *(const short8*)(bwh + 31 * 32);
  bl_n = *(const short8*)(bwl + 31 * 32);
  asm volatile("s_waitcnt vmcnt(5)" ::: "memory");
  bar();
  projstep(slot, bh, bl);
  bar();
  ++slot; if (slot == 3) slot = 0;
  // ks = 31: newer than STAGE(31): B(31)x2 = 2
  asm volatile("s_waitcnt vmcnt(2)" ::: "memory");
  bar();
  projstep(slot, bh_n, bl_n);

  // ---------------- h epilogue -> swizzled LDS exchange ----------------
  float bias = pb[nt0 * 16 + c];
#pragma unroll
  for (int mt = 0; mt < 2; ++mt) {
    f32x4 a = mt ? acc1 : acc0;
#pragma unroll
    for (int r = 0; r < 4; ++r) {
      float val = a[r] + bias;  // C: row=(q*4+r), col=c
      int row = mt * 16 + q * 4 + r;
      unsigned colb = (unsigned)((nt0 * 16 + c) * 2);
      unsigned o = (unsigned)(row * 128) + (colb ^ ((unsigned)(row & 7) << 4));
      unsigned short h = f32_to_bf16(val);
      *(unsigned short*)((char*)&hxh[0][0] + o) = h;
      *(unsigned short*)((char*)&hxl[0][0] + o) = f32_to_bf16(val - bf16_to_f32(h));
    }
  }
  __syncthreads();

  // agg A-frags (persist in VGPRs for both passes)
  short8 Ahi[2][2], Alo[2][2];
#pragma unroll
  for (int mt = 0; mt < 2; ++mt) {
    int row = mt * 16 + c;
    unsigned rs = (unsigned)((row & 7) << 4);
#pragma unroll
    for (int k2 = 0; k2 < 2; ++k2) {
      unsigned o = (unsigned)(row * 128) + (((unsigned)(k2 * 64 + q * 16)) ^ rs);
      Ahi[mt][k2] = *(const short8*)((const char*)&hxh[0][0] + o);
      Alo[mt][k2] = *(const short8*)((const char*)&hxl[0][0] + o);
    }
  }

  const size_t ebq = (size_t)c * 64 + q * 8;
  auto ebase = [&](int i) { return (size_t)(w + 4 * i) * 1024 + ebq; };

  // ---------------- pass 1: segment Z ----------------
  f32x4 zacc0 = {0.f, 0.f, 0.f, 0.f}, zacc1 = {0.f, 0.f, 0.f, 0.f};
  auto zflush = [&](int seg) {
#pragma unroll
    for (int mt = 0; mt < 2; ++mt)
#pragma unroll
      for (int r = 0; r < 4; ++r) {
        float v = mt ? zacc1[r] : zacc0[r];
        v += __shfl_xor(v, 1); v += __shfl_xor(v, 2);
        v += __shfl_xor(v, 4); v += __shfl_xor(v, 8);
        if (c == 0) zpart[w][mt * 16 + q * 4 + r][seg] = v;
      }
    zacc0 = (f32x4){0.f, 0.f, 0.f, 0.f};
    zacc1 = (f32x4){0.f, 0.f, 0.f, 0.f};
  };

  short8 e0h, e1h, e0l, e1l, n0h, n1h, n0l, n1l;
  {
    size_t eb = ebase(0);
    e0h = *(const short8*)(ehi + eb); e1h = *(const short8*)(ehi + eb + 32);
    e0l = *(const short8*)(elo + eb); e1l = *(const short8*)(elo + eb + 32);
  }
  int cur_seg = 0;
  for (int i = 0; i < 15; ++i) {
    int nt = w + 4 * i;
    int s = (nt < 32) ? 0 : (nt < 48) ? 1 : (nt < 56) ? 2 : 3;
    if (s != cur_seg) { zflush(cur_seg); cur_seg = s; }
    if (i < 14) {
      size_t eb = ebase(i + 1);
      n0h = *(const short8*)(ehi + eb); n1h = *(const short8*)(ehi + eb + 32);
      n0l = *(const short8*)(elo + eb); n1l = *(const short8*)(elo + eb + 32);
    }
#pragma unroll
    for (int mt = 0; mt < 2; ++mt) {
      f32x4 l = {0.f, 0.f, 0.f, 0.f};
      l = MFMA(Ahi[mt][0], e0h, l); l = MFMA(Ahi[mt][1], e1h, l);
      l = MFMA(Ahi[mt][0], e0l, l); l = MFMA(Ahi[mt][1], e1l, l);
      l = MFMA(Alo[mt][0], e0h, l); l = MFMA(Alo[mt][1], e1h, l);
#pragma unroll
      for (int r = 0; r < 4; ++r) {
        if (mt == 0) zacc0[r] += __expf(l[r]); else zacc1[r] += __expf(l[r]);
      }
    }
    e0h = n0h; e1h = n1h; e0l = n0l; e1l = n1l;
  }
  zflush(cur_seg);
  __syncthreads();
  if (tid < 128) {  // combine: 128 threads = 32 rows x 4 segs
    int row = tid & 31, sg = tid >> 5;
    float Z = zpart[0][row][sg] + zpart[1][row][sg] + zpart[2][row][sg] + zpart[3][row][sg];
    coefL[row][sg] = imp[row0 + row] / Z;
  }
  __syncthreads();

  // ---------------- pass 2: weighted exp accumulation ----------------
  const int bIdx = row0 >> 12;
  f32x4 cf0, cf1;
  int cs2 = -1;
  {
    size_t eb = ebase(0);
    e0h = *(const short8*)(ehi + eb); e1h = *(const short8*)(ehi + eb + 32);
    e0l = *(const short8*)(elo + eb); e1l = *(const short8*)(elo + eb + 32);
  }
  for (int i = 0; i < 15; ++i) {
    int nt = w + 4 * i;
    int s = (nt < 32) ? 0 : (nt < 48) ? 1 : (nt < 56) ? 2 : 3;
    if (s != cs2) {
#pragma unroll
      for (int r = 0; r < 4; ++r) {
        cf0[r] = coefL[q * 4 + r][s];
        cf1[r] = coefL[16 + q * 4 + r][s];
      }
      cs2 = s;
    }
    if (i < 14) {
      size_t eb = ebase(i + 1);
      n0h = *(const short8*)(ehi + eb); n1h = *(const short8*)(ehi + eb + 32);
      n0l = *(const short8*)(elo + eb); n1l = *(const short8*)(elo + eb + 32);
    }
    float wsum = 0.f;
#pragma unroll
    for (int mt = 0; mt < 2; ++mt) {
      f32x4 l = {0.f, 0.f, 0.f, 0.f};
      l = MFMA(Ahi[mt][0], e0h, l); l = MFMA(Ahi[mt][1], e1h, l);
      l = MFMA(Ahi[mt][0], e0l, l); l = MFMA(Ahi[mt][1], e1l, l);
      l = MFMA(Alo[mt][0], e0h, l); l = MFMA(Alo[mt][1], e1h, l);
#pragma unroll
      for (int r = 0; r < 4; ++r)
        wsum = fmaf(__expf(l[r]), mt ? cf1[r] : cf0[r], wsum);
    }
    wsum += __shfl_xor(wsum, 16);
    wsum += __shfl_xor(wsum, 32);  // lanes sharing col c now hold all 32 rows' sum
    if (lane < 16) atomicAdd(&wg[bIdx * 960 + nt * 16 + c], wsum);
    e0h = n0h; e1h = n1h; e0l = n0l; e1l = n1l;
  }
}

// ---- k_topk: parallel rank-based selection + ballot emission ----
__global__ __launch_bounds__(256) void k_topk(const float* __restrict__ wg,
                                              float* __restrict__ out) {
  __shared__ float vals[512];
  __shared__ int flags[512];
  int blk = blockIdx.x;
  int b = blk >> 2, t = blk & 3;
  int tid = threadIdx.x;
  const int Ns[4] = {512, 256, 128, 64};
  const int Ks[4] = {64, 32, 16, 3};
  const int Off[4] = {0, 512, 768, 896};
  int N = Ns[t], K = Ks[t], off = Off[t];
  for (int n = tid; n < N; n += 256) vals[n] = wg[b * 960 + off + n];
  __syncthreads();
  for (int n = tid; n < N; n += 256) {
    float v = vals[n];
    int rank = 0;
    for (int m = 0; m < N; ++m) {  // LDS broadcast reads, fully parallel
      float u = vals[m];
      rank += (u > v || (u == v && m < n)) ? 1 : 0;
    }
    flags[n] = (rank < K) ? 1 : 0;
  }
  __syncthreads();
  if (t <= 1) {  // index outputs: sorted ascending via ballot prefix (wave 0)
    if (tid < 64) {
      int base = 0;
      for (int ch = 0; ch < N; ch += 64) {
        int n = ch + tid;
        int f = flags[n];
        unsigned long long mask = __ballot(f);
        if (f) {
          int pos = base + __popcll(mask & ((1ull << tid) - 1ull));
          if (t == 0) out[b * 64 + pos] = (float)n;
          else out[512 + b * 32 + pos] = (float)n;
        }
        base += __popcll(mask);
      }
    }
  } else if (t == 2) {  // rel_Q and rel_K (identical sparse vectors)
    for (int n = tid; n < 128; n += 256) {
      float v = flags[n] ? vals[n] : 0.f;
      out[768 + b * 128 + n] = v;
      out[1792 + b * 128 + n] = v;
    }
  } else {  // val_w
    for (int n = tid; n < 64; n += 256) {
      float v = flags[n] ? vals[n] : 0.f;
      out[2816 + b * 64 + n] = v;
    }
  }
}

extern "C" void kernel_launch(void* const* d_in, const int* in_sizes, int n_in,
                              void* d_out, int out_size, void* d_ws, size_t ws_size,
                              hipStream_t stream) {
  const float* x   = (const float*)d_in[0];   // 8*4096*1024
  const float* imp = (const float*)d_in[1];   // 8*4096
  const float* pw  = (const float*)d_in[2];   // 64*1024
  const float* pb  = (const float*)d_in[3];   // 64
  const float* emb = (const float*)d_in[4];   // 1216*64
  float* out = (float*)d_out;                 // 3328 floats

  char* ws = (char*)d_ws;
  unsigned short* whi = (unsigned short*)(ws);             // 128 KiB
  unsigned short* wlo = (unsigned short*)(ws + 131072);    // 128 KiB
  unsigned short* ehi = (unsigned short*)(ws + 262144);    // 120 KiB
  unsigned short* elo = (unsigned short*)(ws + 385024);    // 120 KiB
  float*          wg  = (float*)(ws + 507904);             // 30 KiB

  hipLaunchKernelGGL(k_prep, dim3(64), dim3(256), 0, stream, pw, emb, whi, wlo, ehi, elo, wg);
  hipLaunchKernelGGL(k_main, dim3(1024), dim3(256), 0, stream, x, whi, wlo, pb, ehi, elo, imp, wg);
  hipLaunchKernelGGL(k_topk, dim3(32), dim3(256), 0, stream, wg, out);
}